// Round 8
// baseline (123.352 us; speedup 1.0000x reference)
//
#include <hip/hip_runtime.h>

#define NTOK 256
#define LOG2E 1.44269504088896340736f
#define LN_EPS 1e-5f

typedef float v4f __attribute__((ext_vector_type(4)));

static __device__ __forceinline__ v4f splat4(float s) {
    v4f r; r.x = s; r.y = s; r.z = s; r.w = s; return r;
}

// quad-perm DPP shuffle (VALU pipe, no LDS): xor1 = [1,0,3,2] = 0xB1,
// xor2 = [2,3,0,1] = 0x4E
template <int CTRL>
static __device__ __forceinline__ float dppq(float v) {
    return __int_as_float(
        __builtin_amdgcn_update_dpp(0, __float_as_int(v), CTRL, 0xF, 0xF, true));
}
static __device__ __forceinline__ v4f quad_sum(v4f v) {
    v4f t;
    t.x = dppq<0xB1>(v.x); t.y = dppq<0xB1>(v.y);
    t.z = dppq<0xB1>(v.z); t.w = dppq<0xB1>(v.w);
    v += t;
    t.x = dppq<0x4E>(v.x); t.y = dppq<0x4E>(v.y);
    t.z = dppq<0x4E>(v.z); t.w = dppq<0x4E>(v.w);
    return v + t;
}
static __device__ __forceinline__ float sel4(v4f v, int kq) {
    float ab = (kq & 1) ? v.y : v.x;
    float cd = (kq & 1) ? v.w : v.z;
    return (kq & 2) ? cd : ab;
}

// Grid: 1024 blocks (1 per batch row) x 256 threads (4 waves), 8 blocks/CU.
// Lane = gl*4 + kq. Query group qg = w*16 + gl owns queries
// {qg, qg+64, qg+128, qg+192} packed in v4f; kq owns key quarter
// [kq*64, kq*64+64). Each wave covers 64 queries x 256 keys independently;
// split-k partials combined with quad DPP shuffles (VALU). KV permuted
// (slot = i*4 + kq) so the wave's 4 broadcast addresses land in disjoint
// bank quads. ONE __syncthreads total.
__global__ __launch_bounds__(256, 8)
void att_decoder_kernel(
    const float* __restrict__ x, const float* __restrict__ m,
    const float* __restrict__ sa_w_in, const float* __restrict__ sa_b_in,
    const float* __restrict__ sa_w_out, const float* __restrict__ sa_b_out,
    const float* __restrict__ ca_w_in, const float* __restrict__ ca_b_in,
    const float* __restrict__ ca_w_out, const float* __restrict__ ca_b_out,
    const float* __restrict__ ln1_g, const float* __restrict__ ln1_b,
    const float* __restrict__ ln2_g, const float* __restrict__ ln2_b,
    const float* __restrict__ ln3_g, const float* __restrict__ ln3_b,
    const float* __restrict__ f_w1, const float* __restrict__ f_b1,
    const float* __restrict__ f_ln_g, const float* __restrict__ f_ln_b,
    const float* __restrict__ f_w2, const float* __restrict__ f_b2,
    float* __restrict__ out)
{
    const int tid  = threadIdx.x;
    const int row  = blockIdx.x;
    const int lane = tid & 63;
    const int w    = tid >> 6;
    const int kq   = lane & 3;
    const int qg   = (w << 4) + (lane >> 2);   // 0..63

    __shared__ float4 kv_sa[NTOK];   // 4 KB, permuted slots
    __shared__ float4 kv_ca[NTOK];   // 4 KB

    const float2* __restrict__ x2 = (const float2*)x;
    const float2* __restrict__ m2 = (const float2*)m;

    // ---- staging: thread tid = slot; key j = (tid>>2) | ((tid&3)<<6).
    // Linear slot writes -> conflict-free ds_write_b128.
    {
        const int j = (tid >> 2) | ((tid & 3) << 6);
        float2 xv = x2[row * NTOK + j];
        float d = 0.5f * (xv.x - xv.y);
        float n = d * rsqrtf(d * d + LN_EPS);
        float h0 =  n * ln1_g[0] + ln1_b[0];
        float h1 = -n * ln1_g[1] + ln1_b[1];
        float4 kv;
        kv.x = h0*sa_w_in[4]  + h1*sa_w_in[5]  + sa_b_in[2];
        kv.y = h0*sa_w_in[6]  + h1*sa_w_in[7]  + sa_b_in[3];
        kv.z = h0*sa_w_in[8]  + h1*sa_w_in[9]  + sa_b_in[4];
        kv.w = h0*sa_w_in[10] + h1*sa_w_in[11] + sa_b_in[5];
        kv_sa[tid] = kv;
        float2 mv = m2[row * NTOK + j];
        kv.x = mv.x*ca_w_in[4]  + mv.y*ca_w_in[5]  + ca_b_in[2];
        kv.y = mv.x*ca_w_in[6]  + mv.y*ca_w_in[7]  + ca_b_in[3];
        kv.z = mv.x*ca_w_in[8]  + mv.y*ca_w_in[9]  + ca_b_in[4];
        kv.w = mv.x*ca_w_in[10] + mv.y*ca_w_in[11] + ca_b_in[5];
        kv_ca[tid] = kv;
    }

    // ---- own 4 queries (v4f components c -> query qg + c*64), LN1 ----
    v4f h0, h1;
    {
        float2 q0 = x2[row * NTOK + qg];
        float2 q1 = x2[row * NTOK + qg + 64];
        float2 q2 = x2[row * NTOK + qg + 128];
        float2 q3 = x2[row * NTOK + qg + 192];
        const float g0 = ln1_g[0], b0 = ln1_b[0], g1 = ln1_g[1], b1 = ln1_b[1];
#define LN1C(QV, C) { float d_ = 0.5f*(QV.x - QV.y);                       \
        float n_ = d_ * rsqrtf(d_*d_ + LN_EPS);                             \
        h0.C = n_*g0 + b0; h1.C = -n_*g1 + b1; }
        LN1C(q0, x) LN1C(q1, y) LN1C(q2, z) LN1C(q3, w)
#undef LN1C
    }

    __syncthreads();   // the only barrier

    const float sc = 0.7071067811865476f * LOG2E;
    const int slot0 = kq;            // slot = i*4 + kq

    // ---- self-attention ----
    {
        v4f qe0 = (h0*splat4(sa_w_in[0]) + h1*splat4(sa_w_in[1]) + splat4(sa_b_in[0])) * splat4(sc);
        v4f qe1 = (h0*splat4(sa_w_in[2]) + h1*splat4(sa_w_in[3]) + splat4(sa_b_in[1])) * splat4(sc);
        v4f l = splat4(0.f), a0 = splat4(0.f), a1 = splat4(0.f);
        #pragma unroll 8
        for (int i = 0; i < 64; ++i) {
            float4 kv = kv_sa[(i << 2) + slot0];
            v4f s = qe0*splat4(kv.x) + qe1*splat4(kv.y);
            v4f p;
            p.x = __builtin_amdgcn_exp2f(s.x);
            p.y = __builtin_amdgcn_exp2f(s.y);
            p.z = __builtin_amdgcn_exp2f(s.z);
            p.w = __builtin_amdgcn_exp2f(s.w);
            l += p; a0 += p*splat4(kv.z); a1 += p*splat4(kv.w);
        }
        l = quad_sum(l); a0 = quad_sum(a0); a1 = quad_sum(a1);
        v4f rl;
        rl.x = 1.0f/l.x; rl.y = 1.0f/l.y; rl.z = 1.0f/l.z; rl.w = 1.0f/l.w;
        a0 *= rl; a1 *= rl;
        h0 += a0*splat4(sa_w_out[0]) + a1*splat4(sa_w_out[1]) + splat4(sa_b_out[0]);
        h1 += a0*splat4(sa_w_out[2]) + a1*splat4(sa_w_out[3]) + splat4(sa_b_out[1]);
    }

    // ---- LN2 (packed) ----
    {
        const float g0 = ln2_g[0], b0 = ln2_b[0], g1 = ln2_g[1], b1 = ln2_b[1];
#define LN2C(C) { float d_ = 0.5f*(h0.C - h1.C);                           \
        float n_ = d_ * rsqrtf(d_*d_ + LN_EPS);                             \
        h0.C = n_*g0 + b0; h1.C = -n_*g1 + b1; }
        LN2C(x) LN2C(y) LN2C(z) LN2C(w)
#undef LN2C
    }

    // ---- cross-attention ----
    v4f cl, ca0, ca1;
    {
        v4f qe0 = (h0*splat4(ca_w_in[0]) + h1*splat4(ca_w_in[1]) + splat4(ca_b_in[0])) * splat4(sc);
        v4f qe1 = (h0*splat4(ca_w_in[2]) + h1*splat4(ca_w_in[3]) + splat4(ca_b_in[1])) * splat4(sc);
        v4f l = splat4(0.f), a0 = splat4(0.f), a1 = splat4(0.f);
        #pragma unroll 8
        for (int i = 0; i < 64; ++i) {
            float4 kv = kv_ca[(i << 2) + slot0];
            v4f s = qe0*splat4(kv.x) + qe1*splat4(kv.y);
            v4f p;
            p.x = __builtin_amdgcn_exp2f(s.x);
            p.y = __builtin_amdgcn_exp2f(s.y);
            p.z = __builtin_amdgcn_exp2f(s.z);
            p.w = __builtin_amdgcn_exp2f(s.w);
            l += p; a0 += p*splat4(kv.z); a1 += p*splat4(kv.w);
        }
        cl = quad_sum(l); ca0 = quad_sum(a0); ca1 = quad_sum(a1);
    }

    // ---- extract this lane's query (component kq) -> scalar epilogue ----
    float L   = sel4(cl, kq);
    float A0  = sel4(ca0, kq) / L;
    float A1  = sel4(ca1, kq) / L;
    float s0  = sel4(h0, kq);
    float s1  = sel4(h1, kq);
    s0 += A0*ca_w_out[0] + A1*ca_w_out[1] + ca_b_out[0];
    s1 += A0*ca_w_out[2] + A1*ca_w_out[3] + ca_b_out[1];

    // ---- LN3 ----
    {
        float d = 0.5f*(s0 - s1);
        float n = d * rsqrtf(d*d + LN_EPS);
        s0 =  n*ln3_g[0] + ln3_b[0];
        s1 = -n*ln3_g[1] + ln3_b[1];
    }

    // ---- FFN: Linear(2,10) -> LN(10) -> ReLU -> Linear(10,2), residual ----
    {
        float ff[10];
        #pragma unroll
        for (int i = 0; i < 10; ++i)
            ff[i] = s0*f_w1[2*i] + s1*f_w1[2*i+1] + f_b1[i];
        float mu = 0.f;
        #pragma unroll
        for (int i = 0; i < 10; ++i) mu += ff[i];
        mu *= 0.1f;
        float var = 0.f;
        #pragma unroll
        for (int i = 0; i < 10; ++i) { float d = ff[i] - mu; var += d * d; }
        var *= 0.1f;
        float r = rsqrtf(var + LN_EPS);
        float o0 = 0.f, o1 = 0.f;
        #pragma unroll
        for (int i = 0; i < 10; ++i) {
            float n = (ff[i] - mu) * r * f_ln_g[i] + f_ln_b[i];
            n = fmaxf(n, 0.f);
            o0 += n * f_w2[i];               // f_w2 is [2,10] row-major
            o1 += n * f_w2[10 + i];
        }
        s0 += o0 + f_b2[0];
        s1 += o1 + f_b2[1];
    }

    // query index = qg + kq*64; per kq, 16 consecutive float2 -> 128B segments
    ((float2*)out)[row * NTOK + qg + (kq << 6)] = make_float2(s0, s1);
}

extern "C" void kernel_launch(void* const* d_in, const int* in_sizes, int n_in,
                              void* d_out, int out_size, void* d_ws, size_t ws_size,
                              hipStream_t stream) {
    const float* x        = (const float*)d_in[0];
    const float* m        = (const float*)d_in[1];
    const float* sa_w_in  = (const float*)d_in[2];
    const float* sa_b_in  = (const float*)d_in[3];
    const float* sa_w_out = (const float*)d_in[4];
    const float* sa_b_out = (const float*)d_in[5];
    const float* ca_w_in  = (const float*)d_in[6];
    const float* ca_b_in  = (const float*)d_in[7];
    const float* ca_w_out = (const float*)d_in[8];
    const float* ca_b_out = (const float*)d_in[9];
    const float* ln1_g    = (const float*)d_in[10];
    const float* ln1_b    = (const float*)d_in[11];
    const float* ln2_g    = (const float*)d_in[12];
    const float* ln2_b    = (const float*)d_in[13];
    const float* ln3_g    = (const float*)d_in[14];
    const float* ln3_b    = (const float*)d_in[15];
    const float* f_w1     = (const float*)d_in[16];
    const float* f_b1     = (const float*)d_in[17];
    const float* f_ln_g   = (const float*)d_in[18];
    const float* f_ln_b   = (const float*)d_in[19];
    const float* f_w2     = (const float*)d_in[20];
    const float* f_b2     = (const float*)d_in[21];

    const int nbatch = in_sizes[0] / (NTOK * 2);   // 1024
    att_decoder_kernel<<<nbatch, 256, 0, stream>>>(
        x, m, sa_w_in, sa_b_in, sa_w_out, sa_b_out,
        ca_w_in, ca_b_in, ca_w_out, ca_b_out,
        ln1_g, ln1_b, ln2_g, ln2_b, ln3_g, ln3_b,
        f_w1, f_b1, f_ln_g, f_ln_b, f_w2, f_b2,
        (float*)d_out);
}

// Round 9
// 121.068 us; speedup vs baseline: 1.0189x; 1.0189x over previous
//
#include <hip/hip_runtime.h>

#define NTOK 256
#define LOG2E 1.44269504088896340736f
#define LN_EPS 1e-5f

typedef float v4f __attribute__((ext_vector_type(4)));

static __device__ __forceinline__ v4f splat4(float s) {
    v4f r; r.x = s; r.y = s; r.z = s; r.w = s; return r;
}

// quad-perm DPP shuffle (VALU pipe): xor1 = 0xB1, xor2 = 0x4E
template <int CTRL>
static __device__ __forceinline__ float dppq(float v) {
    return __int_as_float(
        __builtin_amdgcn_update_dpp(0, __float_as_int(v), CTRL, 0xF, 0xF, true));
}
static __device__ __forceinline__ v4f quad_sum(v4f v) {
    v4f t;
    t.x = dppq<0xB1>(v.x); t.y = dppq<0xB1>(v.y);
    t.z = dppq<0xB1>(v.z); t.w = dppq<0xB1>(v.w);
    v += t;
    t.x = dppq<0x4E>(v.x); t.y = dppq<0x4E>(v.y);
    t.z = dppq<0x4E>(v.z); t.w = dppq<0x4E>(v.w);
    return v + t;
}
static __device__ __forceinline__ float sel4(v4f v, int kq) {
    float ab = (kq & 1) ? v.y : v.x;
    float cd = (kq & 1) ? v.w : v.z;
    return (kq & 2) ? cd : ab;
}
static __device__ __forceinline__ v4f rcp4(v4f v) {
    v4f r;
    r.x = __builtin_amdgcn_rcpf(v.x); r.y = __builtin_amdgcn_rcpf(v.y);
    r.z = __builtin_amdgcn_rcpf(v.z); r.w = __builtin_amdgcn_rcpf(v.w);
    return r;
}

// Rank-reduced fused decoder layer.
// SA: post-LN1 token = (n*g0+b0, -n*g1+b1) -> keys/values linear in scalar n.
//     score = A_q*n_k (+B_q dropped: softmax-invariant). Track S0=sum p,
//     S1=sum p*n; attn = alpha_v*(S1/S0)+beta_v. 4 ops/pair, 4 B/key in LDS.
// CA: score = C0*m0 + C1*m1 (+C2 dropped). Track T0,T1,T2 = sum p, p*m0,
//     p*m1; attn reconstructed from value-weight algebra. 8 B/key in LDS.
// Geometry = R8 (validated): 1024 blocks x 256 thr; lane = qg*4+kq;
// quad-DPP split-k combine; ONE barrier.
__global__ __launch_bounds__(256, 8)
void att_decoder_kernel(
    const float* __restrict__ x, const float* __restrict__ m,
    const float* __restrict__ sa_w_in, const float* __restrict__ sa_b_in,
    const float* __restrict__ sa_w_out, const float* __restrict__ sa_b_out,
    const float* __restrict__ ca_w_in, const float* __restrict__ ca_b_in,
    const float* __restrict__ ca_w_out, const float* __restrict__ ca_b_out,
    const float* __restrict__ ln1_g, const float* __restrict__ ln1_b,
    const float* __restrict__ ln2_g, const float* __restrict__ ln2_b,
    const float* __restrict__ ln3_g, const float* __restrict__ ln3_b,
    const float* __restrict__ f_w1, const float* __restrict__ f_b1,
    const float* __restrict__ f_ln_g, const float* __restrict__ f_ln_b,
    const float* __restrict__ f_w2, const float* __restrict__ f_b2,
    float* __restrict__ out)
{
    const int tid  = threadIdx.x;
    const int row  = blockIdx.x;
    const int lane = tid & 63;
    const int w    = tid >> 6;
    const int kq   = lane & 3;
    const int qg   = (w << 4) + (lane >> 2);   // 0..63

    __shared__ float  n_sa[NTOK];    // 1 KB: LN1 scalar per key
    __shared__ float2 mca [NTOK];    // 2 KB: raw m per key

    const float2* __restrict__ x2 = (const float2*)x;
    const float2* __restrict__ m2 = (const float2*)m;

    const float g0 = ln1_g[0], b0 = ln1_b[0], g1 = ln1_g[1], b1 = ln1_b[1];

    // ---- staging: thread tid -> slot tid holds key j = (tid>>2)|((tid&3)<<6)
    {
        const int j = (tid >> 2) | ((tid & 3) << 6);
        float2 xv = x2[row * NTOK + j];
        float d = 0.5f * (xv.x - xv.y);
        n_sa[tid] = d * rsqrtf(d * d + LN_EPS);
        mca[tid]  = m2[row * NTOK + j];
    }

    // ---- own 4 queries: LN1 scalar nq per component ----
    v4f nq;
    {
        float2 q0 = x2[row * NTOK + qg];
        float2 q1 = x2[row * NTOK + qg + 64];
        float2 q2 = x2[row * NTOK + qg + 128];
        float2 q3 = x2[row * NTOK + qg + 192];
#define LNQ(QV, C) { float d_ = 0.5f*(QV.x - QV.y);                         \
        nq.C = d_ * rsqrtf(d_*d_ + LN_EPS); }
        LNQ(q0, x) LNQ(q1, y) LNQ(q2, z) LNQ(q3, w)
#undef LNQ
    }
    v4f h0 = nq * splat4(g0) + splat4(b0);
    v4f h1 = nq * splat4(-g1) + splat4(b1);

    __syncthreads();   // the only barrier

    const float sc = 0.7071067811865476f * LOG2E;
    const int slot0 = kq;

    // ---- self-attention (rank-1) ----
    {
        // key/value linearization coeffs (block-uniform -> SGPR)
        const float ak0 = g0*sa_w_in[4] - g1*sa_w_in[5];
        const float ak1 = g0*sa_w_in[6] - g1*sa_w_in[7];
        const float av0 = g0*sa_w_in[8] - g1*sa_w_in[9];
        const float bv0 = b0*sa_w_in[8] + b1*sa_w_in[9] + sa_b_in[4];
        const float av1 = g0*sa_w_in[10] - g1*sa_w_in[11];
        const float bv1 = b0*sa_w_in[10] + b1*sa_w_in[11] + sa_b_in[5];
        v4f qh0 = h0*splat4(sa_w_in[0]) + h1*splat4(sa_w_in[1]) + splat4(sa_b_in[0]);
        v4f qh1 = h0*splat4(sa_w_in[2]) + h1*splat4(sa_w_in[3]) + splat4(sa_b_in[1]);
        v4f A = (qh0*splat4(ak0) + qh1*splat4(ak1)) * splat4(sc);
        v4f S0 = splat4(0.f), S1 = splat4(0.f);
        #pragma unroll 8
        for (int i = 0; i < 64; ++i) {
            float n = n_sa[(i << 2) + slot0];     // quad-spread ds_read_b32
            v4f s = A * splat4(n);
            v4f p;
            p.x = __builtin_amdgcn_exp2f(s.x);
            p.y = __builtin_amdgcn_exp2f(s.y);
            p.z = __builtin_amdgcn_exp2f(s.z);
            p.w = __builtin_amdgcn_exp2f(s.w);
            S0 += p;
            S1 += p * splat4(n);
        }
        S0 = quad_sum(S0); S1 = quad_sum(S1);
        v4f R = S1 * rcp4(S0);
        v4f a0 = splat4(av0)*R + splat4(bv0);
        v4f a1 = splat4(av1)*R + splat4(bv1);
        h0 += a0*splat4(sa_w_out[0]) + a1*splat4(sa_w_out[1]) + splat4(sa_b_out[0]);
        h1 += a0*splat4(sa_w_out[2]) + a1*splat4(sa_w_out[3]) + splat4(sa_b_out[1]);
    }

    // ---- LN2 (per component) ----
    {
        const float G0 = ln2_g[0], B0 = ln2_b[0], G1 = ln2_g[1], B1 = ln2_b[1];
#define LN2C(C) { float d_ = 0.5f*(h0.C - h1.C);                            \
        float n_ = d_ * rsqrtf(d_*d_ + LN_EPS);                              \
        h0.C = n_*G0 + B0; h1.C = -n_*G1 + B1; }
        LN2C(x) LN2C(y) LN2C(z) LN2C(w)
#undef LN2C
    }

    // ---- cross-attention (rank-2, C2 dropped) ----
    v4f T0, T1, T2;
    {
        v4f qh0 = h0*splat4(ca_w_in[0]) + h1*splat4(ca_w_in[1]) + splat4(ca_b_in[0]);
        v4f qh1 = h0*splat4(ca_w_in[2]) + h1*splat4(ca_w_in[3]) + splat4(ca_b_in[1]);
        v4f C0 = (qh0*splat4(ca_w_in[4]) + qh1*splat4(ca_w_in[6])) * splat4(sc);
        v4f C1 = (qh0*splat4(ca_w_in[5]) + qh1*splat4(ca_w_in[7])) * splat4(sc);
        T0 = splat4(0.f); T1 = splat4(0.f); T2 = splat4(0.f);
        #pragma unroll 8
        for (int i = 0; i < 64; ++i) {
            float2 mv = mca[(i << 2) + slot0];    // quad-spread ds_read_b64
            v4f s = C0*splat4(mv.x) + C1*splat4(mv.y);
            v4f p;
            p.x = __builtin_amdgcn_exp2f(s.x);
            p.y = __builtin_amdgcn_exp2f(s.y);
            p.z = __builtin_amdgcn_exp2f(s.z);
            p.w = __builtin_amdgcn_exp2f(s.w);
            T0 += p;
            T1 += p * splat4(mv.x);
            T2 += p * splat4(mv.y);
        }
        T0 = quad_sum(T0); T1 = quad_sum(T1); T2 = quad_sum(T2);
    }

    // ---- extract this lane's token (component kq), scalar epilogue ----
    float rT  = __builtin_amdgcn_rcpf(sel4(T0, kq));
    float U1  = sel4(T1, kq) * rT;
    float U2  = sel4(T2, kq) * rT;
    // CA values: v = W_v m + b_v with rows ca_w_in[8..9],[10..11], b ca_b_in[4..5]
    float A0  = ca_w_in[8]*U1  + ca_w_in[9]*U2  + ca_b_in[4];
    float A1  = ca_w_in[10]*U1 + ca_w_in[11]*U2 + ca_b_in[5];
    float s0  = sel4(h0, kq);
    float s1  = sel4(h1, kq);
    s0 += A0*ca_w_out[0] + A1*ca_w_out[1] + ca_b_out[0];
    s1 += A0*ca_w_out[2] + A1*ca_w_out[3] + ca_b_out[1];

    // ---- LN3 ----
    {
        float d = 0.5f*(s0 - s1);
        float n = d * rsqrtf(d*d + LN_EPS);
        s0 =  n*ln3_g[0] + ln3_b[0];
        s1 = -n*ln3_g[1] + ln3_b[1];
    }

    // ---- FFN: Linear(2,10) -> LN(10) -> ReLU -> Linear(10,2), residual ----
    {
        float ff[10];
        #pragma unroll
        for (int i = 0; i < 10; ++i)
            ff[i] = s0*f_w1[2*i] + s1*f_w1[2*i+1] + f_b1[i];
        float mu = 0.f;
        #pragma unroll
        for (int i = 0; i < 10; ++i) mu += ff[i];
        mu *= 0.1f;
        float var = 0.f;
        #pragma unroll
        for (int i = 0; i < 10; ++i) { float d = ff[i] - mu; var += d * d; }
        var *= 0.1f;
        float r = rsqrtf(var + LN_EPS);
        float o0 = 0.f, o1 = 0.f;
        #pragma unroll
        for (int i = 0; i < 10; ++i) {
            float n = (ff[i] - mu) * r * f_ln_g[i] + f_ln_b[i];
            n = fmaxf(n, 0.f);
            o0 += n * f_w2[i];               // f_w2 is [2,10] row-major
            o1 += n * f_w2[10 + i];
        }
        s0 += o0 + f_b2[0];
        s1 += o1 + f_b2[1];
    }

    ((float2*)out)[row * NTOK + qg + (kq << 6)] = make_float2(s0, s1);
}

extern "C" void kernel_launch(void* const* d_in, const int* in_sizes, int n_in,
                              void* d_out, int out_size, void* d_ws, size_t ws_size,
                              hipStream_t stream) {
    const float* x        = (const float*)d_in[0];
    const float* m        = (const float*)d_in[1];
    const float* sa_w_in  = (const float*)d_in[2];
    const float* sa_b_in  = (const float*)d_in[3];
    const float* sa_w_out = (const float*)d_in[4];
    const float* sa_b_out = (const float*)d_in[5];
    const float* ca_w_in  = (const float*)d_in[6];
    const float* ca_b_in  = (const float*)d_in[7];
    const float* ca_w_out = (const float*)d_in[8];
    const float* ca_b_out = (const float*)d_in[9];
    const float* ln1_g    = (const float*)d_in[10];
    const float* ln1_b    = (const float*)d_in[11];
    const float* ln2_g    = (const float*)d_in[12];
    const float* ln2_b    = (const float*)d_in[13];
    const float* ln3_g    = (const float*)d_in[14];
    const float* ln3_b    = (const float*)d_in[15];
    const float* f_w1     = (const float*)d_in[16];
    const float* f_b1     = (const float*)d_in[17];
    const float* f_ln_g   = (const float*)d_in[18];
    const float* f_ln_b   = (const float*)d_in[19];
    const float* f_w2     = (const float*)d_in[20];
    const float* f_b2     = (const float*)d_in[21];

    const int nbatch = in_sizes[0] / (NTOK * 2);   // 1024
    att_decoder_kernel<<<nbatch, 256, 0, stream>>>(
        x, m, sa_w_in, sa_b_in, sa_w_out, sa_b_out,
        ca_w_in, ca_b_in, ca_w_out, ca_b_out,
        ln1_g, ln1_b, ln2_g, ln2_b, ln3_g, ln3_b,
        f_w1, f_b1, f_ln_g, f_ln_b, f_w2, f_b2,
        (float*)d_out);
}